// Round 3
// baseline (874.913 us; speedup 1.0000x reference)
//
#include <hip/hip_runtime.h>
#include <hip/hip_bf16.h>

#define HH 192
#define WW 192
#define HW 36864           // 192*192
#define CHW 2359296        // 64*36864

typedef __attribute__((ext_vector_type(8))) short short8;
typedef __attribute__((ext_vector_type(4))) float float4v;

static __device__ __forceinline__ unsigned short f2bu(float f) {
  union { float f; unsigned u; } v; v.f = f;
  unsigned r = (v.u + 0x7fffu + ((v.u >> 16) & 1u)) >> 16;   // RNE bf16
  return (unsigned short)r;
}

static __device__ __forceinline__ float bu2f(unsigned short s) {
  union { unsigned u; float f; } v; v.u = ((unsigned)s) << 16;
  return v.f;
}

// ---------------------------------------------------------------- prep ----
__global__ void k_prep(const float* __restrict__ c1w, const float* __restrict__ c2w,
                       const float* __restrict__ wfuse,
                       unsigned short* __restrict__ wB1, unsigned short* __restrict__ wB2,
                       float* __restrict__ wfT, float* __restrict__ tmp,
                       float* __restrict__ u01) {
  int i = blockIdx.x * 256 + threadIdx.x;
  if (i < 147456) {
    int T = i / 9216, r = i % 9216;
    int s = r / 512, e = r % 512;
    int l = e >> 3, j = e & 7;
    int m = l & 15, q = l >> 4;
    int oc = T * 16 + m;
    int k = s * 32 + q * 8 + j;
    int tap = k >> 6, ic = k & 63;
    int ky = tap / 3, kx = tap % 3;
    wB1[i] = f2bu(c1w[((oc * 64 + ic) * 3 + ky) * 3 + kx]);
    return;
  }
  int j2 = i - 147456;
  if (j2 < 16384) {
    int g = j2 / 512, e = j2 % 512;
    int l = e >> 3, jj = e & 7;
    int m = l & 15, q = l >> 4;
    int w = g / 8, s2 = g % 8;
    wB2[j2] = f2bu(c2w[(w * 16 + m) * 256 + s2 * 32 + q * 8 + jj]);
    return;
  }
  int k3 = j2 - 16384;
  if (k3 < 131072) { int jj = k3 >> 8, r = k3 & 255; wfT[k3] = wfuse[r * 512 + jj]; return; }
  int z = k3 - 131072;
  if (z < 65536) { tmp[z] = 0.f; return; }
  int v = z - 65536;
  if (v < 294912) u01[v] = 0.f;     // u0 then u1 (contiguous in ws)
}

// ---------------------------------------------------- init polys + out0 ----
__global__ void k_init_polys(const float* __restrict__ wh, const int* __restrict__ ct_ind,
                             const int* __restrict__ ct_img,
                             float* __restrict__ initp, float* __restrict__ out0) {
  int n = blockIdx.x;     // 0..127
  int p = threadIdx.x;    // 0..127
  int ind = ct_ind[n], img = ct_img[n];
  int cx = ind % WW, cy = ind / WW;
  size_t base = ((size_t)(img * 256 + 2 * p)) * HW + (size_t)cy * WW + cx;
  float ox = wh[base];
  float oy = wh[base + HW];
  float px = __fadd_rn(__fmul_rn(ox, 10.0f), (float)cx);
  float py = __fadd_rn(__fmul_rn(oy, 10.0f), (float)cy);
  initp[n * 256 + 2 * p]     = px;
  initp[n * 256 + 2 * p + 1] = py;
  out0[n * 256 + 2 * p]      = __fmul_rn(px, 4.0f);
  out0[n * 256 + 2 * p + 1]  = __fmul_rn(py, 4.0f);
}

// ------------------------------------------- fused conv1+relu+conv2+gate ----
// v3: LDS diet for 4 blocks/CU (was 2: Occupancy 18%, MfmaUtil 11.5%).
//  - conv2 split into two 64-px phases: y1S = [64][264] bf16 (33.8 KB)
//    instead of [128][264] (67.5 KB). Max LDS region = stage 38 KB -> 4
//    blocks/CU. Pixel-split keeps VGPR peak ~128 (acc1[0..3] dies before
//    acc2a is born).
//  - halo stage vectorized: float4 global loads (16 iters, shift/mask
//    addressing) + 2-iter scalar tail for halo columns. Same values.
__global__ __launch_bounds__(256, 4) void k_conv(const float* __restrict__ x,
    const unsigned short* __restrict__ wB1, const float* __restrict__ b1,
    const unsigned short* __restrict__ wB2, const float* __restrict__ b2,
    const float* __restrict__ u0, float* __restrict__ feat,
    unsigned short* __restrict__ featT) {
  int blk = blockIdx.x;            // 4 * 96 * 3
  int b    = blk / 288;
  int rem  = blk % 288;
  int pair = rem / 3;
  int xs   = rem % 3;
  int y0 = pair * 2, x0 = xs * 64;
  int t = threadIdx.x;
  int w = t >> 6, l = t & 63;
  int m = l & 15, q = l >> 4;

  __shared__ __align__(16) unsigned short sb[19008];   // 38.0 KB union buffer

  // ---- stage x halo: 4 rows x 66 px x 64 ic -> bf16 [(row*66+xx)*72 + ic]
  // main: xx 1..64 (gx = x0..x0+63, always in-bounds in x) via float4
  {
    int kq = t & 15;          // quad column: xx = 1 + kq*4 + d
    int pr = t >> 4;          // (r,ic) pair slot
    for (int itr = 0; itr < 16; ++itr) {
      int pi = itr * 16 + pr;       // 0..255
      int r  = pi >> 6;             // 0..3
      int ic = pi & 63;
      int gy = y0 + r - 1;
      float4v v = (float4v){0.f, 0.f, 0.f, 0.f};
      if (gy >= 0 && gy < HH)
        v = *(const float4v*)&x[(size_t)(b * 64 + ic) * HW + (size_t)gy * WW + x0 + kq * 4];
      int base = (r * 66 + 1 + kq * 4) * 72 + ic;
      sb[base]       = f2bu(v[0]);
      sb[base + 72]  = f2bu(v[1]);
      sb[base + 144] = f2bu(v[2]);
      sb[base + 216] = f2bu(v[3]);
    }
    // halo columns xx=0 (gx=x0-1) and xx=65 (gx=x0+64)
    for (int itr = 0; itr < 2; ++itr) {
      int e = itr * 256 + t;       // 0..511
      int xxh = e >> 8;            // 0 or 1
      int rm = e & 255;
      int r = rm >> 6, ic = rm & 63;
      int gy = y0 + r - 1;
      int gx = x0 - 1 + xxh * 65;
      float v = 0.f;
      if (gy >= 0 && gy < HH && gx >= 0 && gx < WW)
        v = x[(size_t)(b * 64 + ic) * HW + (size_t)gy * WW + gx];
      sb[(r * 66 + xxh * 65) * 72 + ic] = f2bu(v);
    }
  }
  __syncthreads();

  // ---- conv1: M=128, N=64 (this wave), K=576
  float4v acc1[8][4];
#pragma unroll
  for (int nt = 0; nt < 4; ++nt) {
    float bv = b1[w * 64 + nt * 16 + m];
#pragma unroll
    for (int mt = 0; mt < 8; ++mt) acc1[mt][nt] = (float4v){bv, bv, bv, bv};
  }

#pragma unroll
  for (int s = 0; s < 18; ++s) {
    int tap = s >> 1, ky = tap / 3, kx = tap - ky * 3;
    int ic0 = (s & 1) * 32 + q * 8;
    short8 bF[4];
#pragma unroll
    for (int nt = 0; nt < 4; ++nt)
      bF[nt] = *(const short8*)&wB1[(size_t)((((w * 4 + nt) * 18 + s) * 512) + l * 8)];
    short8 aF[8];
#pragma unroll
    for (int mt = 0; mt < 8; ++mt) {
      int col  = (mt & 3) * 16 + m + kx;
      int rowi = ky + (mt >> 2);
      aF[mt] = *(const short8*)&sb[(rowi * 66 + col) * 72 + ic0];
    }
#pragma unroll
    for (int nt = 0; nt < 4; ++nt)
#pragma unroll
      for (int mt = 0; mt < 8; ++mt)
        acc1[mt][nt] = __builtin_amdgcn_mfma_f32_16x16x32_bf16(aF[mt], bF[nt], acc1[mt][nt], 0, 0, 0);
  }
  __syncthreads();                       // all xS reads done

  // ---- phase A: y1 (relu, bf16) px 0..63 -> LDS [p*264 + oc]
#pragma unroll
  for (int mt = 0; mt < 4; ++mt)
#pragma unroll
    for (int nt = 0; nt < 4; ++nt)
#pragma unroll
      for (int r = 0; r < 4; ++r) {
        int p = mt * 16 + q * 4 + r;           // 0..63
        int oc = w * 64 + nt * 16 + m;
        sb[p * 264 + oc] = f2bu(fmaxf(acc1[mt][nt][r], 0.f));
      }
  __syncthreads();

  // ---- conv2-A: px 0..63, K=256
  float4v acc2a[4];
  {
    float bv = b2[w * 16 + m];
#pragma unroll
    for (int mt = 0; mt < 4; ++mt) acc2a[mt] = (float4v){bv, bv, bv, bv};
  }
#pragma unroll
  for (int s2 = 0; s2 < 8; ++s2) {
    short8 bF2 = *(const short8*)&wB2[(size_t)(((w * 8 + s2) * 512) + l * 8)];
#pragma unroll
    for (int mt = 0; mt < 4; ++mt) {
      short8 a2 = *(const short8*)&sb[(mt * 16 + m) * 264 + s2 * 32 + q * 8];
      acc2a[mt] = __builtin_amdgcn_mfma_f32_16x16x32_bf16(a2, bF2, acc2a[mt], 0, 0, 0);
    }
  }
  __syncthreads();                       // A reads done

  // ---- phase B: y1 px 64..127 -> LDS rows 0..63
#pragma unroll
  for (int mt = 4; mt < 8; ++mt)
#pragma unroll
    for (int nt = 0; nt < 4; ++nt)
#pragma unroll
      for (int r = 0; r < 4; ++r) {
        int p = mt * 16 + q * 4 + r;           // 64..127
        int oc = w * 64 + nt * 16 + m;
        sb[(p - 64) * 264 + oc] = f2bu(fmaxf(acc1[mt][nt][r], 0.f));
      }
  __syncthreads();

  // ---- conv2-B: px 64..127
  float4v acc2b[4];
  {
    float bv = b2[w * 16 + m];
#pragma unroll
    for (int mt = 0; mt < 4; ++mt) acc2b[mt] = (float4v){bv, bv, bv, bv};
  }
#pragma unroll
  for (int s2 = 0; s2 < 8; ++s2) {
    short8 bF2 = *(const short8*)&wB2[(size_t)(((w * 8 + s2) * 512) + l * 8)];
#pragma unroll
    for (int mt = 0; mt < 4; ++mt) {
      short8 a2 = *(const short8*)&sb[(mt * 16 + m) * 264 + s2 * 32 + q * 8];
      acc2b[mt] = __builtin_amdgcn_mfma_f32_16x16x32_bf16(a2, bF2, acc2b[mt], 0, 0, 0);
    }
  }
  __syncthreads();                       // B reads done before fS overwrite

  // ---- epilogue: transpose via LDS (wave-private region)
  float* fS = (float*)sb;                // per-wave 16c x 128px (pad 132)
#pragma unroll
  for (int mt = 0; mt < 8; ++mt)
#pragma unroll
    for (int r = 0; r < 4; ++r) {
      int p = mt * 16 + q * 4 + r;
      float v = (mt < 4) ? acc2a[mt][r] : acc2b[mt - 4][r];
      fS[w * 2112 + m * 132 + p] = v;
    }
  const float* ub = u0 + b * HW;
  // pass 1: NCHW fp32 feat, coalesced over px
#pragma unroll
  for (int i = 0; i < 32; ++i) {
    int idx = i * 64 + l;
    int c16 = idx >> 7, p = idx & 127;
    float f = fS[w * 2112 + c16 * 132 + p];
    int gy = y0 + (p >> 6), gx = x0 + (p & 63);
    float uu = ub[gy * WW + gx];
    feat[(size_t)(b * 64 + w * 16 + c16) * HW + (size_t)gy * WW + gx] = fmaxf(uu * f + f, 0.f);
  }
  // pass 2: channel-last bf16 shadow featT[(b*HW+gy*WW+gx)*64 + ch]
  {
    unsigned short* ft = featT + (size_t)b * HW * 64;
    int c2 = (l & 7) * 2;
#pragma unroll
    for (int i = 0; i < 16; ++i) {
      int p = (l >> 3) + 8 * i;
      float f0 = fS[w * 2112 + c2 * 132 + p];
      float f1 = fS[w * 2112 + (c2 + 1) * 132 + p];
      int gy = y0 + (p >> 6), gx = x0 + (p & 63);
      float uu = ub[gy * WW + gx];
      f0 = fmaxf(uu * f0 + f0, 0.f);
      f1 = fmaxf(uu * f1 + f1, 0.f);
      unsigned v = (unsigned)f2bu(f0) | ((unsigned)f2bu(f1) << 16);
      *(unsigned*)&ft[((size_t)(gy * WW + gx)) * 64 + w * 16 + c2] = v;
    }
  }
}

// ------------------------------------------------------ point-in-polygon ----
__global__ __launch_bounds__(64) void k_pnp(const float* __restrict__ polys,
                                            float* __restrict__ outm,
                                            float* __restrict__ u) {
  int row  = blockIdx.x;   // 0..191
  int n    = blockIdx.y;   // 0..63
  int lane = threadIdx.x;
  __shared__ float vx[128], vy[128], xint[128];
  __shared__ int cnt;
  if (lane == 0) cnt = 0;
  vx[lane]      = polys[n * 256 + 2 * lane];
  vy[lane]      = polys[n * 256 + 2 * lane + 1];
  vx[lane + 64] = polys[n * 256 + 2 * (lane + 64)];
  vy[lane + 64] = polys[n * 256 + 2 * (lane + 64) + 1];
  __syncthreads();
  float yy = (float)row;
  for (int e = lane; e < 128; e += 64) {
    float y1 = vy[e], y2 = vy[(e + 1) & 127];
    if ((y1 > yy) != (y2 > yy)) {
      float x1 = vx[e], x2 = vx[(e + 1) & 127];
      float den = __fsub_rn(y2, y1);
      if (fabsf(den) < 1e-9f) den = 1e-9f;
      float xi = __fadd_rn(x1, __fdiv_rn(__fmul_rn(__fsub_rn(x2, x1), __fsub_rn(yy, y1)), den));
      xint[atomicAdd(&cnt, 1)] = xi;
    }
  }
  __syncthreads();
  int mm = cnt;
  int bb = (n < 32) ? 0 : 1;
  int cc = n & 31;
  size_t base = ((size_t)(bb * 32 + cc) * HH + row) * WW;
  for (int xp = lane; xp < WW; xp += 64) {
    float xf = (float)xp;
    int c = 0;
    for (int j = 0; j < mm; ++j) c += (xf < xint[j]) ? 1 : 0;
    float mv = (float)(c & 1);
    outm[base + xp] = mv;
    if (n >= 32) {
      outm[base + (size_t)32 * HW + xp] = mv;
      outm[base + (size_t)64 * HW + xp] = mv;
    }
    if (c & 1) {
      int off = bb * HW + row * WW + xp;
      atomicOr((int*)(u + off), 0x3f800000);
      if (n >= 32) {
        atomicOr((int*)(u + off + HW), 0x3f800000);
        atomicOr((int*)(u + off + 2 * HW), 0x3f800000);
      }
    }
  }
}

// ------------------------------------------------------- bilinear sample ----
__global__ __launch_bounds__(256) void k_sample(const unsigned short* __restrict__ featT,
    const float* __restrict__ initp, const int* __restrict__ ct_ind,
    const int* __restrict__ ct_img, float* __restrict__ fp) {
  int n  = blockIdx.x;             // 0..127
  int ch = blockIdx.y;             // 0..1  (channel half)
  int t  = threadIdx.x;            // 0..255
  int w  = t >> 6, lane = t & 63;
  int c  = lane & 31;              // channel offset within half
  int ph = lane >> 5;              // which of the wave's 2 points

  __shared__ float sF[4128];       // [32c][129p], idx = c*129 + p

  int img = ct_img[n];
  int ind = ct_ind[n];
  float ctx = (float)(ind % WW), cty = (float)(ind / WW);
  const unsigned short* fb = featT + (size_t)img * HW * 64 + ch * 32 + c;

  for (int i = 0; i < 17; ++i) {
    int p = i * 8 + w * 2 + ph;    // point index 0..135 (guard <129)
    if (p < 129) {
      float px, py;
      if (p == 0) { px = ctx; py = cty; }
      else {
        px = initp[n * 256 + 2 * (p - 1)];
        py = initp[n * 256 + 2 * (p - 1) + 1];
      }
      float x = __fsub_rn(px, 0.5f), y = __fsub_rn(py, 0.5f);
      float x0f = floorf(x), y0f = floorf(y);
      float wx = __fsub_rn(x, x0f), wy = __fsub_rn(y, y0f);
      int x0 = (int)x0f, y0 = (int)y0f;
      float g[4];
#pragma unroll
      for (int qq = 0; qq < 4; ++qq) {
        int xi = x0 + (qq & 1), yi = y0 + (qq >> 1);
        bool valid = (xi >= 0) && (xi < WW) && (yi >= 0) && (yi < HH);
        int xc = min(max(xi, 0), WW - 1), yc = min(max(yi, 0), HH - 1);
        float v = bu2f(fb[(size_t)(yc * WW + xc) * 64]);
        g[qq] = valid ? v : 0.f;
      }
      float omx = __fsub_rn(1.f, wx), omy = __fsub_rn(1.f, wy);
      float r = __fadd_rn(__fadd_rn(__fadd_rn(
          __fmul_rn(__fmul_rn(g[0], omx), omy),
          __fmul_rn(__fmul_rn(g[1], wx),  omy)),
          __fmul_rn(__fmul_rn(g[2], omx), wy)),
          __fmul_rn(__fmul_rn(g[3], wx),  wy));
      sF[c * 129 + p] = r;
    }
  }
  __syncthreads();
  float* dst = fp + (size_t)n * 8256 + (size_t)ch * 4128;
  for (int idx = t; idx < 4128; idx += 256) dst[idx] = sF[idx];
}

// ------------------------------------------------- GEMM1: tmp = fp @ Wp^T ----
__global__ __launch_bounds__(256) void k_gemm1(const float* __restrict__ fp,
    const float* __restrict__ wpoly, float* __restrict__ tmp) {
  int ntile = blockIdx.x;   // 0..1
  int jtile = blockIdx.y;   // 0..7
  int ks    = blockIdx.z;   // 0..31
  int c0 = (129 * ks) / 32, c1 = (129 * (ks + 1)) / 32;
  int t = threadIdx.x;
  int tn = t & 15, tj = t >> 4;
  __shared__ float aS[64][65];
  __shared__ float bS[64][65];
  float acc[4][4];
#pragma unroll
  for (int i = 0; i < 4; ++i)
#pragma unroll
    for (int j = 0; j < 4; ++j) acc[i][j] = 0.f;
  for (int ch = c0; ch < c1; ++ch) {
    int k0 = ch * 64;
    __syncthreads();
    for (int idx = t; idx < 4096; idx += 256) {
      int r = idx >> 6, cc = idx & 63;
      aS[cc][r] = fp[(size_t)(ntile * 64 + r) * 8256 + k0 + cc];
      bS[cc][r] = wpoly[(size_t)(jtile * 64 + r) * 8256 + k0 + cc];
    }
    __syncthreads();
    for (int kk = 0; kk < 64; ++kk) {
      float a0 = aS[kk][tn * 4], a1 = aS[kk][tn * 4 + 1], a2 = aS[kk][tn * 4 + 2], a3 = aS[kk][tn * 4 + 3];
      float b0 = bS[kk][tj * 4], b1 = bS[kk][tj * 4 + 1], b2 = bS[kk][tj * 4 + 2], b3 = bS[kk][tj * 4 + 3];
      acc[0][0] = fmaf(a0, b0, acc[0][0]); acc[0][1] = fmaf(a0, b1, acc[0][1]);
      acc[0][2] = fmaf(a0, b2, acc[0][2]); acc[0][3] = fmaf(a0, b3, acc[0][3]);
      acc[1][0] = fmaf(a1, b0, acc[1][0]); acc[1][1] = fmaf(a1, b1, acc[1][1]);
      acc[1][2] = fmaf(a1, b2, acc[1][2]); acc[1][3] = fmaf(a1, b3, acc[1][3]);
      acc[2][0] = fmaf(a2, b0, acc[2][0]); acc[2][1] = fmaf(a2, b1, acc[2][1]);
      acc[2][2] = fmaf(a2, b2, acc[2][2]); acc[2][3] = fmaf(a2, b3, acc[2][3]);
      acc[3][0] = fmaf(a3, b0, acc[3][0]); acc[3][1] = fmaf(a3, b1, acc[3][1]);
      acc[3][2] = fmaf(a3, b2, acc[3][2]); acc[3][3] = fmaf(a3, b3, acc[3][3]);
    }
  }
#pragma unroll
  for (int i = 0; i < 4; ++i)
#pragma unroll
    for (int j = 0; j < 4; ++j)
      atomicAdd(&tmp[(size_t)(ntile * 64 + tn * 4 + i) * 512 + jtile * 64 + tj * 4 + j], acc[i][j]);
}

// -------------------------------------- GEMM2 + coarse assembly + out1 ----
__global__ __launch_bounds__(256) void k_gemm2(const float* __restrict__ tmp,
    const float* __restrict__ wfT, const float* __restrict__ bfuse,
    const float* __restrict__ initp, float* __restrict__ coarse, float* __restrict__ out1) {
  int n = blockIdx.x, r = threadIdx.x;
  __shared__ float tS[512];
  tS[r] = tmp[n * 512 + r];
  tS[r + 256] = tmp[n * 512 + 256 + r];
  __syncthreads();
  float acc = 0.f;
  for (int j = 0; j < 512; ++j) acc = fmaf(wfT[j * 256 + r], tS[j], acc);
  acc = __fadd_rn(acc, bfuse[r]);
  float cr = __fadd_rn(__fmul_rn(acc, 4.0f), initp[n * 256 + r]);
  coarse[n * 256 + r] = cr;
  out1[n * 256 + r] = __fmul_rn(cr, 4.0f);
}

// -------------------------------------------------------------- final feat ----
__global__ void k_final(float* __restrict__ feat, const float* __restrict__ u) {
  size_t i = ((size_t)blockIdx.x * 256 + threadIdx.x) * 4;  // 9437184 total
  int b = (int)(i / ((size_t)CHW));
  int yx = (int)(i % HW);
  float4v f = *(float4v*)&feat[i];
  float4v uu = *(const float4v*)&u[b * HW + yx];
  float4v o;
#pragma unroll
  for (int j = 0; j < 4; ++j) o[j] = fmaxf(__fadd_rn(__fmul_rn(uu[j], f[j]), f[j]), 0.f);
  *(float4v*)&feat[i] = o;
}

extern "C" void kernel_launch(void* const* d_in, const int* in_sizes, int n_in,
                              void* d_out, int out_size, void* d_ws, size_t ws_size,
                              hipStream_t stream) {
  const float* wh    = (const float*)d_in[0];
  const float* cnnf  = (const float*)d_in[1];
  const float* c1w   = (const float*)d_in[2];
  const float* c1b   = (const float*)d_in[3];
  const float* c2w   = (const float*)d_in[4];
  const float* c2b   = (const float*)d_in[5];
  const float* wpoly = (const float*)d_in[6];
  const float* wfuse = (const float*)d_in[7];
  const float* bfuse = (const float*)d_in[8];
  const int* ct_ind  = (const int*)d_in[9];
  const int* ct_img  = (const int*)d_in[10];

  float* ws    = (float*)d_ws;
  float* wfT   = ws;               // 131072 fp32
  float* initp = wfT + 131072;     // 32768
  float* coarse= initp + 32768;    // 32768
  float* tmp   = coarse + 32768;   // 65536
  float* u0    = tmp + 65536;      // 147456
  float* u1    = u0 + 147456;      // 147456 (u0,u1 contiguous for k_prep zero)
  float* fpbuf = u1 + 147456;      // 1056768
  unsigned short* wB1 = (unsigned short*)(fpbuf + 1056768);  // 147456 bf16
  unsigned short* wB2 = wB1 + 147456;                        // 16384 bf16
  // total ~6.8 MB

  float* out0 = (float*)d_out;         // init_polys*4   32768
  float* out1 = out0 + 32768;          // coarse*4       32768
  float* out2 = out1 + 32768;          // mb_init        4718592
  float* out3 = out2 + 4718592;        // mb_c           4718592
  float* out4 = out3 + 4718592;        // feat           9437184
  float* feat = out4;                  // feat scratch lives in out4 (fp32)
  // featT (bf16 channel-last shadow of gated feat) borrows out3's storage:
  // k_sample reads it, then the second k_pnp fully overwrites out3 with mb_c.
  unsigned short* featT = (unsigned short*)out3;

  k_prep<<<2560, 256, 0, stream>>>(c1w, c2w, wfuse, wB1, wB2, wfT, tmp, u0);
  k_init_polys<<<128, 128, 0, stream>>>(wh, ct_ind, ct_img, initp, out0);
  k_pnp<<<dim3(192, 64), 64, 0, stream>>>(initp, out2, u0);
  k_conv<<<1152, 256, 0, stream>>>(cnnf, wB1, c1b, wB2, c2b, u0, feat, featT);
  k_sample<<<dim3(128, 2), 256, 0, stream>>>(featT, initp, ct_ind, ct_img, fpbuf);
  k_gemm1<<<dim3(2, 8, 32), 256, 0, stream>>>(fpbuf, wpoly, tmp);
  k_gemm2<<<128, 256, 0, stream>>>(tmp, wfT, bfuse, initp, coarse, out1);
  k_pnp<<<dim3(192, 64), 64, 0, stream>>>(coarse, out3, u1);
  k_final<<<9216, 256, 0, stream>>>(feat, u1);
}

// Round 4
// 423.654 us; speedup vs baseline: 2.0652x; 2.0652x over previous
//
#include <hip/hip_runtime.h>
#include <hip/hip_bf16.h>

#define HH 192
#define WW 192
#define HW 36864           // 192*192
#define CHW 2359296        // 64*36864

typedef __attribute__((ext_vector_type(8))) short short8;
typedef __attribute__((ext_vector_type(4))) float float4v;

static __device__ __forceinline__ unsigned short f2bu(float f) {
  union { float f; unsigned u; } v; v.f = f;
  unsigned r = (v.u + 0x7fffu + ((v.u >> 16) & 1u)) >> 16;   // RNE bf16
  return (unsigned short)r;
}

static __device__ __forceinline__ float bu2f(unsigned short s) {
  union { unsigned u; float f; } v; v.u = ((unsigned)s) << 16;
  return v.f;
}

// ---------------------------------------------------------------- prep ----
__global__ void k_prep(const float* __restrict__ c1w, const float* __restrict__ c2w,
                       const float* __restrict__ wfuse,
                       unsigned short* __restrict__ wB1, unsigned short* __restrict__ wB2,
                       float* __restrict__ wfT, float* __restrict__ tmp,
                       float* __restrict__ u01) {
  int i = blockIdx.x * 256 + threadIdx.x;
  if (i < 147456) {
    int T = i / 9216, r = i % 9216;
    int s = r / 512, e = r % 512;
    int l = e >> 3, j = e & 7;
    int m = l & 15, q = l >> 4;
    int oc = T * 16 + m;
    int k = s * 32 + q * 8 + j;
    int tap = k >> 6, ic = k & 63;
    int ky = tap / 3, kx = tap % 3;
    wB1[i] = f2bu(c1w[((oc * 64 + ic) * 3 + ky) * 3 + kx]);
    return;
  }
  int j2 = i - 147456;
  if (j2 < 16384) {
    int g = j2 / 512, e = j2 % 512;
    int l = e >> 3, jj = e & 7;
    int m = l & 15, q = l >> 4;
    int w = g / 8, s2 = g % 8;
    wB2[j2] = f2bu(c2w[(w * 16 + m) * 256 + s2 * 32 + q * 8 + jj]);
    return;
  }
  int k3 = j2 - 16384;
  if (k3 < 131072) { int jj = k3 >> 8, r = k3 & 255; wfT[k3] = wfuse[r * 512 + jj]; return; }
  int z = k3 - 131072;
  if (z < 65536) { tmp[z] = 0.f; return; }
  int v = z - 65536;
  if (v < 294912) u01[v] = 0.f;     // u0 then u1 (contiguous in ws)
}

// ---------------------------------------------------- init polys + out0 ----
__global__ void k_init_polys(const float* __restrict__ wh, const int* __restrict__ ct_ind,
                             const int* __restrict__ ct_img,
                             float* __restrict__ initp, float* __restrict__ out0) {
  int n = blockIdx.x;     // 0..127
  int p = threadIdx.x;    // 0..127
  int ind = ct_ind[n], img = ct_img[n];
  int cx = ind % WW, cy = ind / WW;
  size_t base = ((size_t)(img * 256 + 2 * p)) * HW + (size_t)cy * WW + cx;
  float ox = wh[base];
  float oy = wh[base + HW];
  float px = __fadd_rn(__fmul_rn(ox, 10.0f), (float)cx);
  float py = __fadd_rn(__fmul_rn(oy, 10.0f), (float)cy);
  initp[n * 256 + 2 * p]     = px;
  initp[n * 256 + 2 * p + 1] = py;
  out0[n * 256 + 2 * p]      = __fmul_rn(px, 4.0f);
  out0[n * 256 + 2 * p + 1]  = __fmul_rn(py, 4.0f);
}

// ------------------------------------------- fused conv1+relu+conv2+gate ----
// v4: register diet instead of LDS diet (round-3 lesson: the 2-block/CU cap
// was the unified VGPR+AGPR budget, not LDS; forcing 4 waves/EU on the old
// M=128 tile spilled: 677MB FETCH, 1.34GB WRITE).
// Tile M=64 px (2 rows x 32 cols), N=256 oc, 4 waves. Per wave:
// acc1[4][4]=64 AGPR + aF[4]+bF[4]=32 VGPR -> ~150 unified, fits 3 waves/EU
// (cap 170). LDS union 33.8 KB (not binding). Same MFMA count & order as v2
// -> absmax must stay bit-identical (6.40625).
__global__ __launch_bounds__(256, 3) void k_conv(const float* __restrict__ x,
    const unsigned short* __restrict__ wB1, const float* __restrict__ b1,
    const unsigned short* __restrict__ wB2, const float* __restrict__ b2,
    const float* __restrict__ u0, float* __restrict__ feat,
    unsigned short* __restrict__ featT) {
  int blk = blockIdx.x;            // 4 * 96 * 6 = 2304
  int b    = blk / 576;
  int rem  = blk % 576;
  int pair = rem / 6;
  int xs   = rem % 6;
  int y0 = pair * 2, x0 = xs * 32;
  int t = threadIdx.x;
  int w = t >> 6, l = t & 63;
  int m = l & 15, q = l >> 4;

  __shared__ __align__(16) unsigned short sb[16896];   // 33.8 KB union buffer

  // ---- stage x halo: 4 rows x 34 px x 64 ic -> bf16 [(r*34+xx)*72 + ic]
  // main: xx 1..32 (gx = x0..x0+31, in-bounds) via float4
  {
    int kq = t & 7;           // quad: xx = 1 + kq*4 + d
    int pr = t >> 3;          // 0..31
    for (int itr = 0; itr < 8; ++itr) {
      int pi = itr * 32 + pr;       // 0..255
      int r  = pi >> 6;             // 0..3
      int ic = pi & 63;
      int gy = y0 + r - 1;
      float4v v = (float4v){0.f, 0.f, 0.f, 0.f};
      if (gy >= 0 && gy < HH)
        v = *(const float4v*)&x[(size_t)(b * 64 + ic) * HW + (size_t)gy * WW + x0 + kq * 4];
      int base = (r * 34 + 1 + kq * 4) * 72 + ic;
      sb[base]       = f2bu(v[0]);
      sb[base + 72]  = f2bu(v[1]);
      sb[base + 144] = f2bu(v[2]);
      sb[base + 216] = f2bu(v[3]);
    }
    // halo columns xx=0 (gx=x0-1) and xx=33 (gx=x0+32)
    for (int itr = 0; itr < 2; ++itr) {
      int e = itr * 256 + t;       // 0..511
      int xxh = e >> 8;            // 0 or 1
      int rm = e & 255;
      int r = rm >> 6, ic = rm & 63;
      int gy = y0 + r - 1;
      int gx = x0 - 1 + xxh * 33;
      float v = 0.f;
      if (gy >= 0 && gy < HH && gx >= 0 && gx < WW)
        v = x[(size_t)(b * 64 + ic) * HW + (size_t)gy * WW + gx];
      sb[(r * 34 + xxh * 33) * 72 + ic] = f2bu(v);
    }
  }
  __syncthreads();

  // ---- conv1: M=64, N=64 (this wave), K=576
  float4v acc1[4][4];
#pragma unroll
  for (int nt = 0; nt < 4; ++nt) {
    float bv = b1[w * 64 + nt * 16 + m];
#pragma unroll
    for (int mt = 0; mt < 4; ++mt) acc1[mt][nt] = (float4v){bv, bv, bv, bv};
  }

#pragma unroll
  for (int s = 0; s < 18; ++s) {
    int tap = s >> 1, ky = tap / 3, kx = tap - ky * 3;
    int ic0 = (s & 1) * 32 + q * 8;
    short8 bF[4];
#pragma unroll
    for (int nt = 0; nt < 4; ++nt)
      bF[nt] = *(const short8*)&wB1[(size_t)((((w * 4 + nt) * 18 + s) * 512) + l * 8)];
    short8 aF[4];
#pragma unroll
    for (int mt = 0; mt < 4; ++mt) {
      int col  = (mt & 1) * 16 + m + kx;          // px = mt*16+m -> (row mt>>1, col)
      int rowi = ky + (mt >> 1);
      aF[mt] = *(const short8*)&sb[(rowi * 34 + col) * 72 + ic0];
    }
#pragma unroll
    for (int nt = 0; nt < 4; ++nt)
#pragma unroll
      for (int mt = 0; mt < 4; ++mt)
        acc1[mt][nt] = __builtin_amdgcn_mfma_f32_16x16x32_bf16(aF[mt], bF[nt], acc1[mt][nt], 0, 0, 0);
  }
  __syncthreads();                       // all xS reads done

  // ---- y1 (relu, bf16) -> LDS [p*264 + oc], p = 0..63
#pragma unroll
  for (int mt = 0; mt < 4; ++mt)
#pragma unroll
    for (int nt = 0; nt < 4; ++nt)
#pragma unroll
      for (int r = 0; r < 4; ++r) {
        int p = mt * 16 + q * 4 + r;           // C/D: row = q*4+reg (M=px)
        int oc = w * 64 + nt * 16 + m;         // col = lane&15 (N=oc)
        sb[p * 264 + oc] = f2bu(fmaxf(acc1[mt][nt][r], 0.f));
      }
  __syncthreads();

  // ---- conv2: M=64, N=16 (this wave), K=256
  float4v acc2[4];
  {
    float bv = b2[w * 16 + m];
#pragma unroll
    for (int mt = 0; mt < 4; ++mt) acc2[mt] = (float4v){bv, bv, bv, bv};
  }
#pragma unroll
  for (int s2 = 0; s2 < 8; ++s2) {
    short8 bF2 = *(const short8*)&wB2[(size_t)(((w * 8 + s2) * 512) + l * 8)];
#pragma unroll
    for (int mt = 0; mt < 4; ++mt) {
      short8 a2 = *(const short8*)&sb[(mt * 16 + m) * 264 + s2 * 32 + q * 8];
      acc2[mt] = __builtin_amdgcn_mfma_f32_16x16x32_bf16(a2, bF2, acc2[mt], 0, 0, 0);
    }
  }
  __syncthreads();                       // y1S reads done before fS overwrite

  // ---- epilogue: transpose via LDS (wave-private region, 16c x 64px pad 68)
  float* fS = (float*)sb;
#pragma unroll
  for (int mt = 0; mt < 4; ++mt)
#pragma unroll
    for (int r = 0; r < 4; ++r) {
      int p = mt * 16 + q * 4 + r;
      fS[w * 1088 + m * 68 + p] = acc2[mt][r];
    }
  const float* ub = u0 + b * HW;
  // pass 1: NCHW fp32 feat; lane = px (fixed), iterate oc
  {
    int gy = y0 + (l >> 5), gx = x0 + (l & 31);
    float uu = ub[gy * WW + gx];
    size_t fb = (size_t)(b * 64 + w * 16) * HW + (size_t)gy * WW + gx;
#pragma unroll
    for (int i = 0; i < 16; ++i) {
      float f = fS[w * 1088 + i * 68 + l];
      feat[fb + (size_t)i * HW] = fmaxf(uu * f + f, 0.f);
    }
  }
  // pass 2: channel-last bf16 shadow featT[(b*HW+gy*WW+gx)*64 + ch]
  {
    unsigned short* ft = featT + (size_t)b * HW * 64;
    int c2 = (l & 7) * 2;
#pragma unroll
    for (int i = 0; i < 8; ++i) {
      int p = (l >> 3) + 8 * i;
      float f0 = fS[w * 1088 + c2 * 68 + p];
      float f1 = fS[w * 1088 + (c2 + 1) * 68 + p];
      int gy = y0 + (p >> 5), gx = x0 + (p & 31);
      float uu = ub[gy * WW + gx];
      f0 = fmaxf(uu * f0 + f0, 0.f);
      f1 = fmaxf(uu * f1 + f1, 0.f);
      unsigned v = (unsigned)f2bu(f0) | ((unsigned)f2bu(f1) << 16);
      *(unsigned*)&ft[((size_t)(gy * WW + gx)) * 64 + w * 16 + c2] = v;
    }
  }
}

// ------------------------------------------------------ point-in-polygon ----
__global__ __launch_bounds__(64) void k_pnp(const float* __restrict__ polys,
                                            float* __restrict__ outm,
                                            float* __restrict__ u) {
  int row  = blockIdx.x;   // 0..191
  int n    = blockIdx.y;   // 0..63
  int lane = threadIdx.x;
  __shared__ float vx[128], vy[128], xint[128];
  __shared__ int cnt;
  if (lane == 0) cnt = 0;
  vx[lane]      = polys[n * 256 + 2 * lane];
  vy[lane]      = polys[n * 256 + 2 * lane + 1];
  vx[lane + 64] = polys[n * 256 + 2 * (lane + 64)];
  vy[lane + 64] = polys[n * 256 + 2 * (lane + 64) + 1];
  __syncthreads();
  float yy = (float)row;
  for (int e = lane; e < 128; e += 64) {
    float y1 = vy[e], y2 = vy[(e + 1) & 127];
    if ((y1 > yy) != (y2 > yy)) {
      float x1 = vx[e], x2 = vx[(e + 1) & 127];
      float den = __fsub_rn(y2, y1);
      if (fabsf(den) < 1e-9f) den = 1e-9f;
      float xi = __fadd_rn(x1, __fdiv_rn(__fmul_rn(__fsub_rn(x2, x1), __fsub_rn(yy, y1)), den));
      xint[atomicAdd(&cnt, 1)] = xi;
    }
  }
  __syncthreads();
  int mm = cnt;
  int bb = (n < 32) ? 0 : 1;
  int cc = n & 31;
  size_t base = ((size_t)(bb * 32 + cc) * HH + row) * WW;
  for (int xp = lane; xp < WW; xp += 64) {
    float xf = (float)xp;
    int c = 0;
    for (int j = 0; j < mm; ++j) c += (xf < xint[j]) ? 1 : 0;
    float mv = (float)(c & 1);
    outm[base + xp] = mv;
    if (n >= 32) {
      outm[base + (size_t)32 * HW + xp] = mv;
      outm[base + (size_t)64 * HW + xp] = mv;
    }
    if (c & 1) {
      int off = bb * HW + row * WW + xp;
      atomicOr((int*)(u + off), 0x3f800000);
      if (n >= 32) {
        atomicOr((int*)(u + off + HW), 0x3f800000);
        atomicOr((int*)(u + off + 2 * HW), 0x3f800000);
      }
    }
  }
}

// ------------------------------------------------------- bilinear sample ----
__global__ __launch_bounds__(256) void k_sample(const unsigned short* __restrict__ featT,
    const float* __restrict__ initp, const int* __restrict__ ct_ind,
    const int* __restrict__ ct_img, float* __restrict__ fp) {
  int n  = blockIdx.x;             // 0..127
  int ch = blockIdx.y;             // 0..1  (channel half)
  int t  = threadIdx.x;            // 0..255
  int w  = t >> 6, lane = t & 63;
  int c  = lane & 31;              // channel offset within half
  int ph = lane >> 5;              // which of the wave's 2 points

  __shared__ float sF[4128];       // [32c][129p], idx = c*129 + p

  int img = ct_img[n];
  int ind = ct_ind[n];
  float ctx = (float)(ind % WW), cty = (float)(ind / WW);
  const unsigned short* fb = featT + (size_t)img * HW * 64 + ch * 32 + c;

  for (int i = 0; i < 17; ++i) {
    int p = i * 8 + w * 2 + ph;    // point index 0..135 (guard <129)
    if (p < 129) {
      float px, py;
      if (p == 0) { px = ctx; py = cty; }
      else {
        px = initp[n * 256 + 2 * (p - 1)];
        py = initp[n * 256 + 2 * (p - 1) + 1];
      }
      float x = __fsub_rn(px, 0.5f), y = __fsub_rn(py, 0.5f);
      float x0f = floorf(x), y0f = floorf(y);
      float wx = __fsub_rn(x, x0f), wy = __fsub_rn(y, y0f);
      int x0 = (int)x0f, y0 = (int)y0f;
      float g[4];
#pragma unroll
      for (int qq = 0; qq < 4; ++qq) {
        int xi = x0 + (qq & 1), yi = y0 + (qq >> 1);
        bool valid = (xi >= 0) && (xi < WW) && (yi >= 0) && (yi < HH);
        int xc = min(max(xi, 0), WW - 1), yc = min(max(yi, 0), HH - 1);
        float v = bu2f(fb[(size_t)(yc * WW + xc) * 64]);
        g[qq] = valid ? v : 0.f;
      }
      float omx = __fsub_rn(1.f, wx), omy = __fsub_rn(1.f, wy);
      float r = __fadd_rn(__fadd_rn(__fadd_rn(
          __fmul_rn(__fmul_rn(g[0], omx), omy),
          __fmul_rn(__fmul_rn(g[1], wx),  omy)),
          __fmul_rn(__fmul_rn(g[2], omx), wy)),
          __fmul_rn(__fmul_rn(g[3], wx),  wy));
      sF[c * 129 + p] = r;
    }
  }
  __syncthreads();
  float* dst = fp + (size_t)n * 8256 + (size_t)ch * 4128;
  for (int idx = t; idx < 4128; idx += 256) dst[idx] = sF[idx];
}

// ------------------------------------------------- GEMM1: tmp = fp @ Wp^T ----
__global__ __launch_bounds__(256) void k_gemm1(const float* __restrict__ fp,
    const float* __restrict__ wpoly, float* __restrict__ tmp) {
  int ntile = blockIdx.x;   // 0..1
  int jtile = blockIdx.y;   // 0..7
  int ks    = blockIdx.z;   // 0..31
  int c0 = (129 * ks) / 32, c1 = (129 * (ks + 1)) / 32;
  int t = threadIdx.x;
  int tn = t & 15, tj = t >> 4;
  __shared__ float aS[64][65];
  __shared__ float bS[64][65];
  float acc[4][4];
#pragma unroll
  for (int i = 0; i < 4; ++i)
#pragma unroll
    for (int j = 0; j < 4; ++j) acc[i][j] = 0.f;
  for (int ch = c0; ch < c1; ++ch) {
    int k0 = ch * 64;
    __syncthreads();
    for (int idx = t; idx < 4096; idx += 256) {
      int r = idx >> 6, cc = idx & 63;
      aS[cc][r] = fp[(size_t)(ntile * 64 + r) * 8256 + k0 + cc];
      bS[cc][r] = wpoly[(size_t)(jtile * 64 + r) * 8256 + k0 + cc];
    }
    __syncthreads();
    for (int kk = 0; kk < 64; ++kk) {
      float a0 = aS[kk][tn * 4], a1 = aS[kk][tn * 4 + 1], a2 = aS[kk][tn * 4 + 2], a3 = aS[kk][tn * 4 + 3];
      float b0 = bS[kk][tj * 4], b1 = bS[kk][tj * 4 + 1], b2 = bS[kk][tj * 4 + 2], b3 = bS[kk][tj * 4 + 3];
      acc[0][0] = fmaf(a0, b0, acc[0][0]); acc[0][1] = fmaf(a0, b1, acc[0][1]);
      acc[0][2] = fmaf(a0, b2, acc[0][2]); acc[0][3] = fmaf(a0, b3, acc[0][3]);
      acc[1][0] = fmaf(a1, b0, acc[1][0]); acc[1][1] = fmaf(a1, b1, acc[1][1]);
      acc[1][2] = fmaf(a1, b2, acc[1][2]); acc[1][3] = fmaf(a1, b3, acc[1][3]);
      acc[2][0] = fmaf(a2, b0, acc[2][0]); acc[2][1] = fmaf(a2, b1, acc[2][1]);
      acc[2][2] = fmaf(a2, b2, acc[2][2]); acc[2][3] = fmaf(a2, b3, acc[2][3]);
      acc[3][0] = fmaf(a3, b0, acc[3][0]); acc[3][1] = fmaf(a3, b1, acc[3][1]);
      acc[3][2] = fmaf(a3, b2, acc[3][2]); acc[3][3] = fmaf(a3, b3, acc[3][3]);
    }
  }
#pragma unroll
  for (int i = 0; i < 4; ++i)
#pragma unroll
    for (int j = 0; j < 4; ++j)
      atomicAdd(&tmp[(size_t)(ntile * 64 + tn * 4 + i) * 512 + jtile * 64 + tj * 4 + j], acc[i][j]);
}

// -------------------------------------- GEMM2 + coarse assembly + out1 ----
__global__ __launch_bounds__(256) void k_gemm2(const float* __restrict__ tmp,
    const float* __restrict__ wfT, const float* __restrict__ bfuse,
    const float* __restrict__ initp, float* __restrict__ coarse, float* __restrict__ out1) {
  int n = blockIdx.x, r = threadIdx.x;
  __shared__ float tS[512];
  tS[r] = tmp[n * 512 + r];
  tS[r + 256] = tmp[n * 512 + 256 + r];
  __syncthreads();
  float acc = 0.f;
  for (int j = 0; j < 512; ++j) acc = fmaf(wfT[j * 256 + r], tS[j], acc);
  acc = __fadd_rn(acc, bfuse[r]);
  float cr = __fadd_rn(__fmul_rn(acc, 4.0f), initp[n * 256 + r]);
  coarse[n * 256 + r] = cr;
  out1[n * 256 + r] = __fmul_rn(cr, 4.0f);
}

// -------------------------------------------------------------- final feat ----
__global__ void k_final(float* __restrict__ feat, const float* __restrict__ u) {
  size_t i = ((size_t)blockIdx.x * 256 + threadIdx.x) * 4;  // 9437184 total
  int b = (int)(i / ((size_t)CHW));
  int yx = (int)(i % HW);
  float4v f = *(float4v*)&feat[i];
  float4v uu = *(const float4v*)&u[b * HW + yx];
  float4v o;
#pragma unroll
  for (int j = 0; j < 4; ++j) o[j] = fmaxf(__fadd_rn(__fmul_rn(uu[j], f[j]), f[j]), 0.f);
  *(float4v*)&feat[i] = o;
}

extern "C" void kernel_launch(void* const* d_in, const int* in_sizes, int n_in,
                              void* d_out, int out_size, void* d_ws, size_t ws_size,
                              hipStream_t stream) {
  const float* wh    = (const float*)d_in[0];
  const float* cnnf  = (const float*)d_in[1];
  const float* c1w   = (const float*)d_in[2];
  const float* c1b   = (const float*)d_in[3];
  const float* c2w   = (const float*)d_in[4];
  const float* c2b   = (const float*)d_in[5];
  const float* wpoly = (const float*)d_in[6];
  const float* wfuse = (const float*)d_in[7];
  const float* bfuse = (const float*)d_in[8];
  const int* ct_ind  = (const int*)d_in[9];
  const int* ct_img  = (const int*)d_in[10];

  float* ws    = (float*)d_ws;
  float* wfT   = ws;               // 131072 fp32
  float* initp = wfT + 131072;     // 32768
  float* coarse= initp + 32768;    // 32768
  float* tmp   = coarse + 32768;   // 65536
  float* u0    = tmp + 65536;      // 147456
  float* u1    = u0 + 147456;      // 147456 (u0,u1 contiguous for k_prep zero)
  float* fpbuf = u1 + 147456;      // 1056768
  unsigned short* wB1 = (unsigned short*)(fpbuf + 1056768);  // 147456 bf16
  unsigned short* wB2 = wB1 + 147456;                        // 16384 bf16
  // total ~6.8 MB

  float* out0 = (float*)d_out;         // init_polys*4   32768
  float* out1 = out0 + 32768;          // coarse*4       32768
  float* out2 = out1 + 32768;          // mb_init        4718592
  float* out3 = out2 + 4718592;        // mb_c           4718592
  float* out4 = out3 + 4718592;        // feat           9437184
  float* feat = out4;                  // feat scratch lives in out4 (fp32)
  // featT (bf16 channel-last shadow of gated feat) borrows out3's storage:
  // k_sample reads it, then the second k_pnp fully overwrites out3 with mb_c.
  unsigned short* featT = (unsigned short*)out3;

  k_prep<<<2560, 256, 0, stream>>>(c1w, c2w, wfuse, wB1, wB2, wfT, tmp, u0);
  k_init_polys<<<128, 128, 0, stream>>>(wh, ct_ind, ct_img, initp, out0);
  k_pnp<<<dim3(192, 64), 64, 0, stream>>>(initp, out2, u0);
  k_conv<<<2304, 256, 0, stream>>>(cnnf, wB1, c1b, wB2, c2b, u0, feat, featT);
  k_sample<<<dim3(128, 2), 256, 0, stream>>>(featT, initp, ct_ind, ct_img, fpbuf);
  k_gemm1<<<dim3(2, 8, 32), 256, 0, stream>>>(fpbuf, wpoly, tmp);
  k_gemm2<<<128, 256, 0, stream>>>(tmp, wfT, bfuse, initp, coarse, out1);
  k_pnp<<<dim3(192, 64), 64, 0, stream>>>(coarse, out3, u1);
  k_final<<<9216, 256, 0, stream>>>(feat, u1);
}